// Round 1
// baseline (1365.441 us; speedup 1.0000x reference)
//
#include <hip/hip_runtime.h>

// Problem constants
#define B_  2
#define S_  1024
#define H_  16
#define DK_ 64
#define D_  1024

static const size_t BSD  = (size_t)B_ * S_ * D_;        // 2,097,152
static const size_t BHSS = (size_t)B_ * H_ * S_ * S_;   // 33,554,432

// ---------------------------------------------------------------------------
// Generic NT GEMM: C[n][m] = sum_k A[n][k] * Bm[m][k]
// A rows stride K, Bm rows stride K, C rows stride ldc.
// Block: 256 threads computes a 64x64 tile; each thread 4x4; BK=16.
// ---------------------------------------------------------------------------
__global__ __launch_bounds__(256) void gemm_nt_kernel(
    const float* __restrict__ A, const float* __restrict__ Bm,
    float* __restrict__ C, int K, int ldc) {
  __shared__ float As[16][68];   // As[kk][row]
  __shared__ float Bs[16][68];   // Bs[kk][col]
  int tid = threadIdx.x;
  int tx = tid & 15, ty = tid >> 4;
  int row0 = blockIdx.y << 6, col0 = blockIdx.x << 6;
  int lrow = tid >> 2;           // 0..63
  int lk = (tid & 3) << 2;       // 0,4,8,12
  const float* Ap = A + (size_t)(row0 + lrow) * K + lk;
  const float* Bp = Bm + (size_t)(col0 + lrow) * K + lk;
  float acc[4][4] = {};
  for (int k0 = 0; k0 < K; k0 += 16) {
    float4 a4 = *(const float4*)(Ap + k0);
    float4 b4 = *(const float4*)(Bp + k0);
    As[lk + 0][lrow] = a4.x; As[lk + 1][lrow] = a4.y;
    As[lk + 2][lrow] = a4.z; As[lk + 3][lrow] = a4.w;
    Bs[lk + 0][lrow] = b4.x; Bs[lk + 1][lrow] = b4.y;
    Bs[lk + 2][lrow] = b4.z; Bs[lk + 3][lrow] = b4.w;
    __syncthreads();
#pragma unroll
    for (int kk = 0; kk < 16; ++kk) {
      float4 av = *(const float4*)&As[kk][ty << 2];
      float4 bv = *(const float4*)&Bs[kk][tx << 2];
      float a_[4] = {av.x, av.y, av.z, av.w};
      float b_[4] = {bv.x, bv.y, bv.z, bv.w};
#pragma unroll
      for (int i = 0; i < 4; ++i)
#pragma unroll
        for (int j = 0; j < 4; ++j)
          acc[i][j] = fmaf(a_[i], b_[j], acc[i][j]);
    }
    __syncthreads();
  }
#pragma unroll
  for (int i = 0; i < 4; ++i) {
    float4 st = make_float4(acc[i][0], acc[i][1], acc[i][2], acc[i][3]);
    *(float4*)&C[(size_t)(row0 + (ty << 2) + i) * ldc + col0 + (tx << 2)] = st;
  }
}

// ---------------------------------------------------------------------------
// Scores: M[b,h,s,t] = sum_d Q[b,s,h,d] * K[b,t,h,d]   (K-dim = 64)
// Q,K stored as [B,S,H,DK] (row-major GEMM proj output). M stored [B,H,S,S].
// grid: (S/64 tcols, S/64 srows, B*H)
// ---------------------------------------------------------------------------
__global__ __launch_bounds__(256) void scores_kernel(
    const float* __restrict__ Q, const float* __restrict__ Km,
    float* __restrict__ Mo) {
  __shared__ float Qs[16][68];
  __shared__ float Ks[16][68];
  int z = blockIdx.z, b = z >> 4, h = z & 15;
  const float* Qb = Q + (size_t)b * S_ * D_ + h * DK_;
  const float* Kb = Km + (size_t)b * S_ * D_ + h * DK_;
  float* Cb = Mo + (size_t)z * S_ * S_;
  int tid = threadIdx.x;
  int tx = tid & 15, ty = tid >> 4;
  int row0 = blockIdx.y << 6, col0 = blockIdx.x << 6;
  int lrow = tid >> 2, lk = (tid & 3) << 2;
  float acc[4][4] = {};
  for (int k0 = 0; k0 < DK_; k0 += 16) {
    float4 a4 = *(const float4*)&Qb[(size_t)(row0 + lrow) * D_ + k0 + lk];
    float4 b4 = *(const float4*)&Kb[(size_t)(col0 + lrow) * D_ + k0 + lk];
    Qs[lk + 0][lrow] = a4.x; Qs[lk + 1][lrow] = a4.y;
    Qs[lk + 2][lrow] = a4.z; Qs[lk + 3][lrow] = a4.w;
    Ks[lk + 0][lrow] = b4.x; Ks[lk + 1][lrow] = b4.y;
    Ks[lk + 2][lrow] = b4.z; Ks[lk + 3][lrow] = b4.w;
    __syncthreads();
#pragma unroll
    for (int kk = 0; kk < 16; ++kk) {
      float4 av = *(const float4*)&Qs[kk][ty << 2];
      float4 bv = *(const float4*)&Ks[kk][tx << 2];
      float a_[4] = {av.x, av.y, av.z, av.w};
      float b_[4] = {bv.x, bv.y, bv.z, bv.w};
#pragma unroll
      for (int i = 0; i < 4; ++i)
#pragma unroll
        for (int j = 0; j < 4; ++j)
          acc[i][j] = fmaf(a_[i], b_[j], acc[i][j]);
    }
    __syncthreads();
  }
#pragma unroll
  for (int i = 0; i < 4; ++i) {
    float4 st = make_float4(acc[i][0], acc[i][1], acc[i][2], acc[i][3]);
    *(float4*)&Cb[(size_t)(row0 + (ty << 2) + i) * S_ + col0 + (tx << 2)] = st;
  }
}

// ---------------------------------------------------------------------------
// conv_t: Mt[b,o,y,x] = bt[o] + sum_{i,ky,kx} prev[b,i,y+ky-1,x+kx-1]*Wt[o,i,ky,kx]
// 16 in ch -> 16 out ch. Block: 16x16 spatial tile, 256 threads.
// Thread computes 4 out-channels x 4 x-pixels.
// grid: (S/16, S/16, B)
// ---------------------------------------------------------------------------
__global__ __launch_bounds__(256) void conv_t_kernel(
    const float* __restrict__ X, const float* __restrict__ W,
    const float* __restrict__ bias, float* __restrict__ Y) {
  __shared__ float tile[16][18][18];  // in-ch, y, x (halo 1)
  __shared__ float wl[144][16];       // wl[i*9+ky*3+kx][o]  (broadcast reads)
  __shared__ float bl[16];
  int b = blockIdx.z;
  int y0 = blockIdx.y << 4, x0 = blockIdx.x << 4;
  int tid = threadIdx.x;
  for (int idx = tid; idx < 16 * 144; idx += 256) {
    int o = idx / 144, kk = idx - o * 144;
    wl[kk][o] = W[idx];
  }
  if (tid < 16) bl[tid] = bias[tid];
  for (int idx = tid; idx < 16 * 324; idx += 256) {
    int c = idx / 324;
    int rem = idx - c * 324;
    int r = rem / 18, cc = rem - r * 18;
    int gy = y0 + r - 1, gx = x0 + cc - 1;
    float val = 0.f;
    if ((unsigned)gy < (unsigned)S_ && (unsigned)gx < (unsigned)S_)
      val = X[((size_t)(b * 16 + c) * S_ + gy) * S_ + gx];
    tile[c][r][cc] = val;
  }
  __syncthreads();
  int pg = tid & 63, og = tid >> 6;     // wave-uniform og -> wl reads broadcast
  int px = (pg & 3) << 2, py = pg >> 2;
  float acc[4][4] = {};
  for (int i = 0; i < 16; ++i) {
#pragma unroll
    for (int ky = 0; ky < 3; ++ky)
#pragma unroll
      for (int kx = 0; kx < 3; ++kx) {
        int kk = i * 9 + ky * 3 + kx;
        float4 wv = *(const float4*)&wl[kk][og << 2];
        float w_[4] = {wv.x, wv.y, wv.z, wv.w};
        float p_[4];
#pragma unroll
        for (int j = 0; j < 4; ++j) p_[j] = tile[i][py + ky][px + kx + j];
#pragma unroll
        for (int oi = 0; oi < 4; ++oi)
#pragma unroll
          for (int j = 0; j < 4; ++j)
            acc[oi][j] = fmaf(w_[oi], p_[j], acc[oi][j]);
      }
  }
#pragma unroll
  for (int oi = 0; oi < 4; ++oi) {
    float bv = bl[(og << 2) + oi];
    float4 st = make_float4(acc[oi][0] + bv, acc[oi][1] + bv,
                            acc[oi][2] + bv, acc[oi][3] + bv);
    *(float4*)&Y[((size_t)(b * 16 + (og << 2) + oi) * S_ + y0 + py) * S_ + x0 + px] = st;
  }
}

// ---------------------------------------------------------------------------
// conv_a: Ma[b,o] = ba[o] + conv3x3 over concat([M (ch 0..15), Mt (ch 16..31)])
// Two phases reuse the same 16-channel tile buffer.
// grid: (S/16, S/16, B). Output written to the A-region of d_out.
// ---------------------------------------------------------------------------
__global__ __launch_bounds__(256) void conv_a_kernel(
    const float* __restrict__ Xm, const float* __restrict__ Xt,
    const float* __restrict__ W, const float* __restrict__ bias,
    float* __restrict__ Y) {
  __shared__ float tile[16][18][18];
  __shared__ float wl[288][16];  // wl[c*9+ky*3+kx][o]
  __shared__ float bl[16];
  int b = blockIdx.z;
  int y0 = blockIdx.y << 4, x0 = blockIdx.x << 4;
  int tid = threadIdx.x;
  for (int idx = tid; idx < 16 * 288; idx += 256) {
    int o = idx / 288, kk = idx - o * 288;
    wl[kk][o] = W[idx];
  }
  if (tid < 16) bl[tid] = bias[tid];
  int pg = tid & 63, og = tid >> 6;
  int px = (pg & 3) << 2, py = pg >> 2;
  float acc[4][4] = {};
  const float* Xs[2] = {Xm, Xt};
  for (int phase = 0; phase < 2; ++phase) {
    const float* X = Xs[phase];
    for (int idx = tid; idx < 16 * 324; idx += 256) {
      int c = idx / 324;
      int rem = idx - c * 324;
      int r = rem / 18, cc = rem - r * 18;
      int gy = y0 + r - 1, gx = x0 + cc - 1;
      float val = 0.f;
      if ((unsigned)gy < (unsigned)S_ && (unsigned)gx < (unsigned)S_)
        val = X[((size_t)(b * 16 + c) * S_ + gy) * S_ + gx];
      tile[c][r][cc] = val;
    }
    __syncthreads();
    for (int i = 0; i < 16; ++i) {
#pragma unroll
      for (int ky = 0; ky < 3; ++ky)
#pragma unroll
        for (int kx = 0; kx < 3; ++kx) {
          int kk = (phase * 16 + i) * 9 + ky * 3 + kx;
          float4 wv = *(const float4*)&wl[kk][og << 2];
          float w_[4] = {wv.x, wv.y, wv.z, wv.w};
          float p_[4];
#pragma unroll
          for (int j = 0; j < 4; ++j) p_[j] = tile[i][py + ky][px + kx + j];
#pragma unroll
          for (int oi = 0; oi < 4; ++oi)
#pragma unroll
            for (int j = 0; j < 4; ++j)
              acc[oi][j] = fmaf(w_[oi], p_[j], acc[oi][j]);
        }
    }
    __syncthreads();  // protect tile before phase-2 reload
  }
#pragma unroll
  for (int oi = 0; oi < 4; ++oi) {
    float bv = bl[(og << 2) + oi];
    float4 st = make_float4(acc[oi][0] + bv, acc[oi][1] + bv,
                            acc[oi][2] + bv, acc[oi][3] + bv);
    *(float4*)&Y[((size_t)(b * 16 + (og << 2) + oi) * S_ + y0 + py) * S_ + x0 + px] = st;
  }
}

// ---------------------------------------------------------------------------
// Softmax over last axis of Ma/32 (in place in A region), then POST-softmax
// masking: A[b,h,s,t] = (mask[b,t]==0) ? -1e9 : softmax_val.
// One 256-thread block per row of 1024. grid: B*H*S = 32768
// ---------------------------------------------------------------------------
__global__ __launch_bounds__(256) void softmax_mask_kernel(
    float* __restrict__ A, const int* __restrict__ mask) {
  __shared__ float redm[4], reds[4];
  int row = blockIdx.x;          // (b*16+h)*1024 + s
  int b = row >> 14;             // / (H*S)
  float* rp = A + (size_t)row * S_;
  int tid = threadIdx.x;
  int t = tid << 2;
  float4 x = *(const float4*)&rp[t];
  const float sc = 1.0f / 32.0f;  // 1/sqrt(D_MODEL)
  x.x *= sc; x.y *= sc; x.z *= sc; x.w *= sc;
  float m = fmaxf(fmaxf(x.x, x.y), fmaxf(x.z, x.w));
#pragma unroll
  for (int off = 32; off; off >>= 1) m = fmaxf(m, __shfl_down(m, off));
  int lane = tid & 63, w = tid >> 6;
  if (lane == 0) redm[w] = m;
  __syncthreads();
  m = fmaxf(fmaxf(redm[0], redm[1]), fmaxf(redm[2], redm[3]));
  float e0 = __expf(x.x - m), e1 = __expf(x.y - m);
  float e2 = __expf(x.z - m), e3 = __expf(x.w - m);
  float s = e0 + e1 + e2 + e3;
#pragma unroll
  for (int off = 32; off; off >>= 1) s += __shfl_down(s, off);
  if (lane == 0) reds[w] = s;
  __syncthreads();
  s = reds[0] + reds[1] + reds[2] + reds[3];
  float inv = 1.0f / s;
  const int* mb = mask + b * S_;
  float4 o;
  o.x = (mb[t + 0] == 0) ? -1e9f : e0 * inv;
  o.y = (mb[t + 1] == 0) ? -1e9f : e1 * inv;
  o.z = (mb[t + 2] == 0) ? -1e9f : e2 * inv;
  o.w = (mb[t + 3] == 0) ? -1e9f : e3 * inv;
  *(float4*)&rp[t] = o;
}

// ---------------------------------------------------------------------------
// ctx: ctx2[b,s,h*64+d] = sum_t A[b,h,s,t] * V[b,t,h,d]
// A layout [B,H,S,S]; V layout [B,S,H,DK]; ctx2 layout [B,S,H*DK].
// grid: (S/64 srow-tiles, B*H)
// ---------------------------------------------------------------------------
__global__ __launch_bounds__(256) void ctx_kernel(
    const float* __restrict__ A, const float* __restrict__ V,
    float* __restrict__ Ctx) {
  __shared__ float As[16][68];  // As[t][s]
  __shared__ float Vs[16][68];  // Vs[t][d]
  int z = blockIdx.y, b = z >> 4, h = z & 15;
  const float* Ab = A + (size_t)z * S_ * S_;
  const float* Vb = V + (size_t)b * S_ * D_ + h * DK_;
  float* Cb = Ctx + (size_t)b * S_ * D_ + h * DK_;
  int tid = threadIdx.x;
  int tx = tid & 15, ty = tid >> 4;
  int row0 = blockIdx.x << 6;
  int lrow = tid >> 2, lk = (tid & 3) << 2;
  int vt = tid >> 4, vd = (tid & 15) << 2;
  float acc[4][4] = {};
  for (int t0 = 0; t0 < S_; t0 += 16) {
    float4 a4 = *(const float4*)&Ab[(size_t)(row0 + lrow) * S_ + t0 + lk];
    As[lk + 0][lrow] = a4.x; As[lk + 1][lrow] = a4.y;
    As[lk + 2][lrow] = a4.z; As[lk + 3][lrow] = a4.w;
    float4 v4 = *(const float4*)&Vb[(size_t)(t0 + vt) * D_ + vd];
    *(float4*)&Vs[vt][vd] = v4;
    __syncthreads();
#pragma unroll
    for (int kk = 0; kk < 16; ++kk) {
      float4 av = *(const float4*)&As[kk][ty << 2];
      float4 bv = *(const float4*)&Vs[kk][tx << 2];
      float a_[4] = {av.x, av.y, av.z, av.w};
      float b_[4] = {bv.x, bv.y, bv.z, bv.w};
#pragma unroll
      for (int i = 0; i < 4; ++i)
#pragma unroll
        for (int j = 0; j < 4; ++j)
          acc[i][j] = fmaf(a_[i], b_[j], acc[i][j]);
    }
    __syncthreads();
  }
#pragma unroll
  for (int i = 0; i < 4; ++i) {
    float4 st = make_float4(acc[i][0], acc[i][1], acc[i][2], acc[i][3]);
    *(float4*)&Cb[(size_t)(row0 + (ty << 2) + i) * D_ + (tx << 2)] = st;
  }
}

// ---------------------------------------------------------------------------
extern "C" void kernel_launch(void* const* d_in, const int* in_sizes, int n_in,
                              void* d_out, int out_size, void* d_ws, size_t ws_size,
                              hipStream_t stream) {
  const float* q    = (const float*)d_in[0];
  const float* k    = (const float*)d_in[1];
  const float* v    = (const float*)d_in[2];
  const int*   mask = (const int*)d_in[3];
  const float* prev = (const float*)d_in[4];
  const float* Wq   = (const float*)d_in[5];
  const float* Wk   = (const float*)d_in[6];
  const float* Wv   = (const float*)d_in[7];
  const float* Wo   = (const float*)d_in[8];
  const float* Wt   = (const float*)d_in[9];
  const float* bt   = (const float*)d_in[10];
  const float* Wa   = (const float*)d_in[11];
  const float* ba   = (const float*)d_in[12];

  float* out0 = (float*)d_out;          // [B,S,D]
  float* Aout = out0 + BSD;             // [B,H,S,S]

  float* ws   = (float*)d_ws;
  float* Qb   = ws;                     // [B,S,H,DK]   2,097,152
  float* Kb   = Qb + BSD;               // [B,S,H,DK]
  float* Vb   = Kb + BSD;               // [B,S,H,DK]
  float* Mb   = Vb + BSD;               // [B,H,S,S]   33,554,432
  float* Mtb  = Mb + BHSS;              // [B,H,S,S]
  float* ctx2 = Mtb + BHSS;             // [B,S,H*DK]

  dim3 blk(256);

  // Projections: C[n][m] = x[n][:] . W[m][:]  -> layout [B,S,H,DK]
  dim3 gProj(D_ / 64, (B_ * S_) / 64);
  hipLaunchKernelGGL(gemm_nt_kernel, gProj, blk, 0, stream, q, Wq, Qb, D_, D_);
  hipLaunchKernelGGL(gemm_nt_kernel, gProj, blk, 0, stream, k, Wk, Kb, D_, D_);
  hipLaunchKernelGGL(gemm_nt_kernel, gProj, blk, 0, stream, v, Wv, Vb, D_, D_);

  // Scores M = Q K^T per head
  dim3 gSc(S_ / 64, S_ / 64, B_ * H_);
  hipLaunchKernelGGL(scores_kernel, gSc, blk, 0, stream, Qb, Kb, Mb);

  // Transmit conv on previous scores
  dim3 gConv(S_ / 16, S_ / 16, B_);
  hipLaunchKernelGGL(conv_t_kernel, gConv, blk, 0, stream, prev, Wt, bt, Mtb);

  // Aggregate conv over concat(M, Mt) -> Ma (written into A region of d_out)
  hipLaunchKernelGGL(conv_a_kernel, gConv, blk, 0, stream, Mb, Mtb, Wa, ba, Aout);

  // Softmax(Ma/32) then post-softmax mask, in place
  hipLaunchKernelGGL(softmax_mask_kernel, dim3(B_ * H_ * S_), blk, 0, stream,
                     Aout, mask);

  // ctx = A @ V  -> [B,S,H*DK]
  dim3 gCtx(S_ / 64, B_ * H_);
  hipLaunchKernelGGL(ctx_kernel, gCtx, blk, 0, stream, Aout, Vb, ctx2);

  // out = ctx2 @ Wo^T
  hipLaunchKernelGGL(gemm_nt_kernel, gProj, blk, 0, stream, ctx2, Wo, out0, D_, D_);
}

// Round 2
// 1006.063 us; speedup vs baseline: 1.3572x; 1.3572x over previous
//
#include <hip/hip_runtime.h>

// Problem constants
#define B_  2
#define S_  1024
#define H_  16
#define DK_ 64
#define D_  1024

static const size_t BSD  = (size_t)B_ * S_ * D_;        // 2,097,152
static const size_t BHSS = (size_t)B_ * H_ * S_ * S_;   // 33,554,432

typedef __attribute__((ext_vector_type(8))) short bf16x8;
typedef __attribute__((ext_vector_type(4))) float floatx4;

__device__ __forceinline__ unsigned short f2bf(float f) {
  unsigned u = __builtin_bit_cast(unsigned, f);
  unsigned r = (u + 0x7FFFu + ((u >> 16) & 1u)) >> 16;
  return (unsigned short)r;
}

// ---------------------------------------------------------------------------
// Generic NT GEMM: C[n][m] = sum_k A[n][k] * Bm[m][k]   (unchanged, fp32)
// ---------------------------------------------------------------------------
__global__ __launch_bounds__(256) void gemm_nt_kernel(
    const float* __restrict__ A, const float* __restrict__ Bm,
    float* __restrict__ C, int K, int ldc) {
  __shared__ float As[16][68];
  __shared__ float Bs[16][68];
  int tid = threadIdx.x;
  int tx = tid & 15, ty = tid >> 4;
  int row0 = blockIdx.y << 6, col0 = blockIdx.x << 6;
  int lrow = tid >> 2;
  int lk = (tid & 3) << 2;
  const float* Ap = A + (size_t)(row0 + lrow) * K + lk;
  const float* Bp = Bm + (size_t)(col0 + lrow) * K + lk;
  float acc[4][4] = {};
  for (int k0 = 0; k0 < K; k0 += 16) {
    float4 a4 = *(const float4*)(Ap + k0);
    float4 b4 = *(const float4*)(Bp + k0);
    As[lk + 0][lrow] = a4.x; As[lk + 1][lrow] = a4.y;
    As[lk + 2][lrow] = a4.z; As[lk + 3][lrow] = a4.w;
    Bs[lk + 0][lrow] = b4.x; Bs[lk + 1][lrow] = b4.y;
    Bs[lk + 2][lrow] = b4.z; Bs[lk + 3][lrow] = b4.w;
    __syncthreads();
#pragma unroll
    for (int kk = 0; kk < 16; ++kk) {
      float4 av = *(const float4*)&As[kk][ty << 2];
      float4 bv = *(const float4*)&Bs[kk][tx << 2];
      float a_[4] = {av.x, av.y, av.z, av.w};
      float b_[4] = {bv.x, bv.y, bv.z, bv.w};
#pragma unroll
      for (int i = 0; i < 4; ++i)
#pragma unroll
        for (int j = 0; j < 4; ++j)
          acc[i][j] = fmaf(a_[i], b_[j], acc[i][j]);
    }
    __syncthreads();
  }
#pragma unroll
  for (int i = 0; i < 4; ++i) {
    float4 st = make_float4(acc[i][0], acc[i][1], acc[i][2], acc[i][3]);
    *(float4*)&C[(size_t)(row0 + (ty << 2) + i) * ldc + col0 + (tx << 2)] = st;
  }
}

// ---------------------------------------------------------------------------
// Scores: M[b,h,s,t] = sum_d Q[b,s,h,d]*K[b,t,h,d]  (unchanged, fp32 planar)
// ---------------------------------------------------------------------------
__global__ __launch_bounds__(256) void scores_kernel(
    const float* __restrict__ Q, const float* __restrict__ Km,
    float* __restrict__ Mo) {
  __shared__ float Qs[16][68];
  __shared__ float Ks[16][68];
  int z = blockIdx.z, b = z >> 4, h = z & 15;
  const float* Qb = Q + (size_t)b * S_ * D_ + h * DK_;
  const float* Kb = Km + (size_t)b * S_ * D_ + h * DK_;
  float* Cb = Mo + (size_t)z * S_ * S_;
  int tid = threadIdx.x;
  int tx = tid & 15, ty = tid >> 4;
  int row0 = blockIdx.y << 6, col0 = blockIdx.x << 6;
  int lrow = tid >> 2, lk = (tid & 3) << 2;
  float acc[4][4] = {};
  for (int k0 = 0; k0 < DK_; k0 += 16) {
    float4 a4 = *(const float4*)&Qb[(size_t)(row0 + lrow) * D_ + k0 + lk];
    float4 b4 = *(const float4*)&Kb[(size_t)(col0 + lrow) * D_ + k0 + lk];
    Qs[lk + 0][lrow] = a4.x; Qs[lk + 1][lrow] = a4.y;
    Qs[lk + 2][lrow] = a4.z; Qs[lk + 3][lrow] = a4.w;
    Ks[lk + 0][lrow] = b4.x; Ks[lk + 1][lrow] = b4.y;
    Ks[lk + 2][lrow] = b4.z; Ks[lk + 3][lrow] = b4.w;
    __syncthreads();
#pragma unroll
    for (int kk = 0; kk < 16; ++kk) {
      float4 av = *(const float4*)&Qs[kk][ty << 2];
      float4 bv = *(const float4*)&Ks[kk][tx << 2];
      float a_[4] = {av.x, av.y, av.z, av.w};
      float b_[4] = {bv.x, bv.y, bv.z, bv.w};
#pragma unroll
      for (int i = 0; i < 4; ++i)
#pragma unroll
        for (int j = 0; j < 4; ++j)
          acc[i][j] = fmaf(a_[i], b_[j], acc[i][j]);
    }
    __syncthreads();
  }
#pragma unroll
  for (int i = 0; i < 4; ++i) {
    float4 st = make_float4(acc[i][0], acc[i][1], acc[i][2], acc[i][3]);
    *(float4*)&Cb[(size_t)(row0 + (ty << 2) + i) * S_ + col0 + (tx << 2)] = st;
  }
}

// ---------------------------------------------------------------------------
// repack16: fp32 planar [b][16][Y][X] -> bf16 channel-fastest [b][y][x][16]
// grid (X/256, Y, B), block 256. Plane reads coalesced; 32B/px writes.
// ---------------------------------------------------------------------------
__global__ __launch_bounds__(256) void repack16_kernel(
    const float* __restrict__ src, unsigned short* __restrict__ dst) {
  int x = (blockIdx.x << 8) + threadIdx.x;
  int y = blockIdx.y, b = blockIdx.z;
  const float* sp = src + ((size_t)b * 16 * S_ + y) * S_ + x;
  unsigned short out[16];
#pragma unroll
  for (int c = 0; c < 16; ++c) out[c] = f2bf(sp[(size_t)c << 20]);
  unsigned short* dp = dst + (((size_t)b * S_ + y) * S_ + x) * 16;
  unsigned wds[8];
#pragma unroll
  for (int i = 0; i < 8; ++i)
    wds[i] = (unsigned)out[2 * i] | ((unsigned)out[2 * i + 1] << 16);
  uint4 v0 = {wds[0], wds[1], wds[2], wds[3]};
  uint4 v1 = {wds[4], wds[5], wds[6], wds[7]};
  *(uint4*)dp = v0;
  *((uint4*)dp + 1) = v1;
}

// ---------------------------------------------------------------------------
// conv_t (MFMA): 16ch -> 16ch 3x3 on prevT (bf16 ch-fastest), taps paired
// into K=32 MFMAs (4 pairs + 1 singleton w/ zeroed upper A).
// Block tile: 64 px (x) x 4 rows (y); 4 waves, wave = one row, 4 segs of 16px.
// Output: Mtbf bf16 ch-fastest [b][y][x][16].
// grid (16, 256, 2)
// ---------------------------------------------------------------------------
__global__ __launch_bounds__(256) void conv_t_mfma_kernel(
    const unsigned short* __restrict__ prevT, const float* __restrict__ Wt,
    const float* __restrict__ bt, unsigned short* __restrict__ Mtbf) {
  __shared__ short Xs[6 * 66 * 24];   // [y6][x66][c16 pad->24]  38,016 B? no: *2B = 19,008 B
  int b = blockIdx.z;
  int x0 = blockIdx.x << 6, y0 = blockIdx.y << 2;
  int tid = threadIdx.x;
  int lane = tid & 63, w = tid >> 6;
  int quad = lane >> 4, xn = lane & 15;

  // stage 6 x 66 x (2 halves of 16B)
  for (int idx = tid; idx < 792; idx += 256) {
    int y = idx / 132;
    int r = idx - y * 132;
    int px = r >> 1, half = r & 1;
    int gy = y0 + y - 1, gx = x0 + px - 1;
    uint4 val = {0u, 0u, 0u, 0u};
    if ((unsigned)gy < (unsigned)S_ && (unsigned)gx < (unsigned)S_) {
      const unsigned short* sp =
          prevT + (((size_t)b * S_ + gy) * S_ + gx) * 16 + half * 8;
      val = *(const uint4*)sp;
    }
    *(uint4*)&Xs[(y * 66 + px) * 24 + half * 8] = val;
  }

  // A fragments: weights, pair p covers taps (2p, 2p+1); p=4 upper half zero
  int m = xn;  // out-channel row of A = lane&15
  bf16x8 afr[5];
#pragma unroll
  for (int p = 0; p < 5; ++p) {
#pragma unroll
    for (int j = 0; j < 8; ++j) {
      int k = quad * 8 + j;
      int t = 2 * p + (k >> 4);
      float wv = 0.f;
      if (t < 9) wv = Wt[(m * 16 + (k & 15)) * 9 + t];
      afr[p][j] = (short)f2bf(wv);
    }
  }
  // B tap per quad: quads 0,1 -> 2p; quads 2,3 -> 2p+1 (clamped)
  int tdy[5], tdx[5];
#pragma unroll
  for (int p = 0; p < 5; ++p) {
    int t = 2 * p + (quad >> 1);
    if (t > 8) t = 8;
    tdy[p] = t / 3;
    tdx[p] = t - tdy[p] * 3;
  }
  float btl[4];
#pragma unroll
  for (int r = 0; r < 4; ++r) btl[r] = bt[quad * 4 + r];

  __syncthreads();

  int y = y0 + w;
#pragma unroll
  for (int seg = 0; seg < 4; ++seg) {
    floatx4 acc = {0.f, 0.f, 0.f, 0.f};
#pragma unroll
    for (int p = 0; p < 5; ++p) {
      const short* bp =
          &Xs[((w + tdy[p]) * 66 + seg * 16 + xn + tdx[p]) * 24 + (quad & 1) * 8];
      bf16x8 bfr = *(const bf16x8*)bp;
      acc = __builtin_amdgcn_mfma_f32_16x16x32_bf16(afr[p], bfr, acc, 0, 0, 0);
    }
    ushort4 pk;
    pk.x = f2bf(acc[0] + btl[0]);
    pk.y = f2bf(acc[1] + btl[1]);
    pk.z = f2bf(acc[2] + btl[2]);
    pk.w = f2bf(acc[3] + btl[3]);
    int gx = x0 + seg * 16 + xn;
    *(ushort4*)&Mtbf[(((size_t)b * S_ + y) * S_ + gx) * 16 + quad * 4] = pk;
  }
}

// ---------------------------------------------------------------------------
// conv_a (MFMA): 32ch -> 16ch 3x3; in = {Mbf ch0-15, Mtbf ch16-31} bf16
// ch-fastest. One K=32 MFMA per tap, 9 taps. Output planar fp32 Ma into Aout.
// Block tile 64x4, 4 waves. grid (16, 256, 2)
// ---------------------------------------------------------------------------
__global__ __launch_bounds__(256) void conv_a_mfma_kernel(
    const unsigned short* __restrict__ Mbf, const unsigned short* __restrict__ Mtbf,
    const float* __restrict__ Wa, const float* __restrict__ ba,
    float* __restrict__ Y) {
  __shared__ short Xs[6 * 66 * 40];   // [y6][x66][c32 pad->40] = 31,680 B
  int b = blockIdx.z;
  int x0 = blockIdx.x << 6, y0 = blockIdx.y << 2;
  int tid = threadIdx.x;
  int lane = tid & 63, w = tid >> 6;
  int quad = lane >> 4, xn = lane & 15;

  // stage 6 x 66 x (4 parts of 16B: M lo, M hi, Mt lo, Mt hi)
  for (int idx = tid; idx < 1584; idx += 256) {
    int y = idx / 264;
    int r = idx - y * 264;
    int px = r >> 2, part = r & 3;
    int gy = y0 + y - 1, gx = x0 + px - 1;
    uint4 val = {0u, 0u, 0u, 0u};
    if ((unsigned)gy < (unsigned)S_ && (unsigned)gx < (unsigned)S_) {
      const unsigned short* base = (part < 2) ? Mbf : Mtbf;
      const unsigned short* sp =
          base + (((size_t)b * S_ + gy) * S_ + gx) * 16 + (part & 1) * 8;
      val = *(const uint4*)sp;
    }
    *(uint4*)&Xs[(y * 66 + px) * 40 + part * 8] = val;
  }

  // A fragments: Wa[o=16][c=32][3][3]; composite k = c (0..31)
  int m = xn;
  bf16x8 afr[9];
#pragma unroll
  for (int t = 0; t < 9; ++t) {
#pragma unroll
    for (int j = 0; j < 8; ++j) {
      int k = quad * 8 + j;
      afr[t][j] = (short)f2bf(Wa[(m * 32 + k) * 9 + t]);
    }
  }
  float bal[4];
#pragma unroll
  for (int r = 0; r < 4; ++r) bal[r] = ba[quad * 4 + r];

  __syncthreads();

  int y = y0 + w;
#pragma unroll
  for (int seg = 0; seg < 4; ++seg) {
    floatx4 acc = {0.f, 0.f, 0.f, 0.f};
#pragma unroll
    for (int t = 0; t < 9; ++t) {
      const int dy = t / 3, dx = t - (t / 3) * 3;
      const short* bp = &Xs[((w + dy) * 66 + seg * 16 + xn + dx) * 40 + quad * 8];
      bf16x8 bfr = *(const bf16x8*)bp;
      acc = __builtin_amdgcn_mfma_f32_16x16x32_bf16(afr[t], bfr, acc, 0, 0, 0);
    }
    int gx = x0 + seg * 16 + xn;
#pragma unroll
    for (int r = 0; r < 4; ++r) {
      int mo = quad * 4 + r;
      Y[(((size_t)b * 16 + mo) * S_ + y) * S_ + gx] = acc[r] + bal[r];
    }
  }
}

// ---------------------------------------------------------------------------
// Softmax over last axis of Ma/32 (in place), then POST-softmax masking.
// ---------------------------------------------------------------------------
__global__ __launch_bounds__(256) void softmax_mask_kernel(
    float* __restrict__ A, const int* __restrict__ mask) {
  __shared__ float redm[4], reds[4];
  int row = blockIdx.x;
  int b = row >> 14;
  float* rp = A + (size_t)row * S_;
  int tid = threadIdx.x;
  int t = tid << 2;
  float4 x = *(const float4*)&rp[t];
  const float sc = 1.0f / 32.0f;
  x.x *= sc; x.y *= sc; x.z *= sc; x.w *= sc;
  float m = fmaxf(fmaxf(x.x, x.y), fmaxf(x.z, x.w));
#pragma unroll
  for (int off = 32; off; off >>= 1) m = fmaxf(m, __shfl_down(m, off));
  int lane = tid & 63, w = tid >> 6;
  if (lane == 0) redm[w] = m;
  __syncthreads();
  m = fmaxf(fmaxf(redm[0], redm[1]), fmaxf(redm[2], redm[3]));
  float e0 = __expf(x.x - m), e1 = __expf(x.y - m);
  float e2 = __expf(x.z - m), e3 = __expf(x.w - m);
  float s = e0 + e1 + e2 + e3;
#pragma unroll
  for (int off = 32; off; off >>= 1) s += __shfl_down(s, off);
  if (lane == 0) reds[w] = s;
  __syncthreads();
  s = reds[0] + reds[1] + reds[2] + reds[3];
  float inv = 1.0f / s;
  const int* mb = mask + b * S_;
  float4 o;
  o.x = (mb[t + 0] == 0) ? -1e9f : e0 * inv;
  o.y = (mb[t + 1] == 0) ? -1e9f : e1 * inv;
  o.z = (mb[t + 2] == 0) ? -1e9f : e2 * inv;
  o.w = (mb[t + 3] == 0) ? -1e9f : e3 * inv;
  *(float4*)&rp[t] = o;
}

// ---------------------------------------------------------------------------
// ctx: ctx2[b,s,h*64+d] = sum_t A[b,h,s,t] * V[b,t,h,d]   (unchanged)
// ---------------------------------------------------------------------------
__global__ __launch_bounds__(256) void ctx_kernel(
    const float* __restrict__ A, const float* __restrict__ V,
    float* __restrict__ Ctx) {
  __shared__ float As[16][68];
  __shared__ float Vs[16][68];
  int z = blockIdx.y, b = z >> 4, h = z & 15;
  const float* Ab = A + (size_t)z * S_ * S_;
  const float* Vb = V + (size_t)b * S_ * D_ + h * DK_;
  float* Cb = Ctx + (size_t)b * S_ * D_ + h * DK_;
  int tid = threadIdx.x;
  int tx = tid & 15, ty = tid >> 4;
  int row0 = blockIdx.x << 6;
  int lrow = tid >> 2, lk = (tid & 3) << 2;
  int vt = tid >> 4, vd = (tid & 15) << 2;
  float acc[4][4] = {};
  for (int t0 = 0; t0 < S_; t0 += 16) {
    float4 a4 = *(const float4*)&Ab[(size_t)(row0 + lrow) * S_ + t0 + lk];
    As[lk + 0][lrow] = a4.x; As[lk + 1][lrow] = a4.y;
    As[lk + 2][lrow] = a4.z; As[lk + 3][lrow] = a4.w;
    float4 v4 = *(const float4*)&Vb[(size_t)(t0 + vt) * D_ + vd];
    *(float4*)&Vs[vt][vd] = v4;
    __syncthreads();
#pragma unroll
    for (int kk = 0; kk < 16; ++kk) {
      float4 av = *(const float4*)&As[kk][ty << 2];
      float4 bv = *(const float4*)&Vs[kk][tx << 2];
      float a_[4] = {av.x, av.y, av.z, av.w};
      float b_[4] = {bv.x, bv.y, bv.z, bv.w};
#pragma unroll
      for (int i = 0; i < 4; ++i)
#pragma unroll
        for (int j = 0; j < 4; ++j)
          acc[i][j] = fmaf(a_[i], b_[j], acc[i][j]);
    }
    __syncthreads();
  }
#pragma unroll
  for (int i = 0; i < 4; ++i) {
    float4 st = make_float4(acc[i][0], acc[i][1], acc[i][2], acc[i][3]);
    *(float4*)&Cb[(size_t)(row0 + (ty << 2) + i) * D_ + (tx << 2)] = st;
  }
}

// ---------------------------------------------------------------------------
extern "C" void kernel_launch(void* const* d_in, const int* in_sizes, int n_in,
                              void* d_out, int out_size, void* d_ws, size_t ws_size,
                              hipStream_t stream) {
  const float* q    = (const float*)d_in[0];
  const float* k    = (const float*)d_in[1];
  const float* v    = (const float*)d_in[2];
  const int*   mask = (const int*)d_in[3];
  const float* prev = (const float*)d_in[4];
  const float* Wq   = (const float*)d_in[5];
  const float* Wk   = (const float*)d_in[6];
  const float* Wv   = (const float*)d_in[7];
  const float* Wo   = (const float*)d_in[8];
  const float* Wt   = (const float*)d_in[9];
  const float* bt   = (const float*)d_in[10];
  const float* Wa   = (const float*)d_in[11];
  const float* ba   = (const float*)d_in[12];

  float* out0 = (float*)d_out;          // [B,S,D]
  float* Aout = out0 + BSD;             // [B,H,S,S]

  float* ws   = (float*)d_ws;
  float* Qb   = ws;                     // [B,S,H,DK]
  float* Kb   = Qb + BSD;
  float* Vb   = Kb + BSD;
  float* ctx2 = Vb + BSD;
  float* Mf   = ctx2 + BSD;             // fp32 planar scores [B,H,S,S] (134 MB)
  unsigned short* Mbf   = (unsigned short*)(Mf + BHSS);       // bf16 [B,S,S,16]
  unsigned short* prevT = (unsigned short*)Mf;                // aliases Mf (dead)
  unsigned short* Mtbf  = (unsigned short*)Mf + BHSS;         // second half of Mf region

  dim3 blk(256);

  // Projections
  dim3 gProj(D_ / 64, (B_ * S_) / 64);
  hipLaunchKernelGGL(gemm_nt_kernel, gProj, blk, 0, stream, q, Wq, Qb, D_, D_);
  hipLaunchKernelGGL(gemm_nt_kernel, gProj, blk, 0, stream, k, Wk, Kb, D_, D_);
  hipLaunchKernelGGL(gemm_nt_kernel, gProj, blk, 0, stream, v, Wv, Vb, D_, D_);

  // Scores (fp32 planar)
  dim3 gSc(S_ / 64, S_ / 64, B_ * H_);
  hipLaunchKernelGGL(scores_kernel, gSc, blk, 0, stream, Qb, Kb, Mf);

  // Repack M -> bf16 ch-fastest (Mf must be fully read before prevT overwrite)
  dim3 gRep(S_ / 256, S_, B_);
  hipLaunchKernelGGL(repack16_kernel, gRep, blk, 0, stream, Mf, Mbf);

  // Repack prev -> bf16 ch-fastest (overwrites Mf region)
  hipLaunchKernelGGL(repack16_kernel, gRep, blk, 0, stream, prev, prevT);

  // conv_t (MFMA) -> Mtbf bf16 ch-fastest
  dim3 gConv(S_ / 64, S_ / 4, B_);
  hipLaunchKernelGGL(conv_t_mfma_kernel, gConv, blk, 0, stream, prevT, Wt, bt, Mtbf);

  // conv_a (MFMA) -> Aout planar fp32
  hipLaunchKernelGGL(conv_a_mfma_kernel, gConv, blk, 0, stream, Mbf, Mtbf, Wa, ba, Aout);

  // Softmax(Ma/32) + post-softmax mask, in place
  hipLaunchKernelGGL(softmax_mask_kernel, dim3(B_ * H_ * S_), blk, 0, stream,
                     Aout, mask);

  // ctx = A @ V
  dim3 gCtx(S_ / 64, B_ * H_);
  hipLaunchKernelGGL(ctx_kernel, gCtx, blk, 0, stream, Aout, Vb, ctx2);

  // out = ctx2 @ Wo^T
  hipLaunchKernelGGL(gemm_nt_kernel, gProj, blk, 0, stream, ctx2, Wo, out0, D_, D_);
}

// Round 3
// 750.673 us; speedup vs baseline: 1.8190x; 1.3402x over previous
//
#include <hip/hip_runtime.h>

// Problem constants
#define B_  2
#define S_  1024
#define H_  16
#define DK_ 64
#define D_  1024

static const size_t BSD  = (size_t)B_ * S_ * D_;        // 2,097,152
static const size_t BHSS = (size_t)B_ * H_ * S_ * S_;   // 33,554,432

typedef __attribute__((ext_vector_type(8))) short bf16x8;
typedef __attribute__((ext_vector_type(4))) float floatx4;

__device__ __forceinline__ unsigned short f2bf(float f) {
  unsigned u = __builtin_bit_cast(unsigned, f);
  unsigned r = (u + 0x7FFFu + ((u >> 16) & 1u)) >> 16;
  return (unsigned short)r;
}

// ---------------------------------------------------------------------------
// Flat fp32 -> bf16 convert (float4 per thread)
// ---------------------------------------------------------------------------
__global__ __launch_bounds__(256) void cvt_bf16_kernel(
    const float* __restrict__ src, unsigned short* __restrict__ dst, int n4) {
  int i = (blockIdx.x << 8) + threadIdx.x;
  if (i >= n4) return;
  float4 v = ((const float4*)src)[i];
  ushort4 o;
  o.x = f2bf(v.x); o.y = f2bf(v.y); o.z = f2bf(v.z); o.w = f2bf(v.w);
  ((ushort4*)dst)[i] = o;
}

// ---------------------------------------------------------------------------
// bf16 NT GEMM (MFMA): C[n][m] = sum_k A[n][k]*Bw[m][k], A,Bw bf16 row-major.
// 64x64 tile, BK=32, 256 thr = 4 waves, wave does 32x32 (2x2 of 16x16x32).
// bf16_out: 1 -> store bf16, 0 -> store fp32.
// grid (Mcols/64, N/64)
// ---------------------------------------------------------------------------
__global__ __launch_bounds__(256) void gemm_bf16_nt_kernel(
    const unsigned short* __restrict__ A, const unsigned short* __restrict__ Bw,
    void* __restrict__ Cout, int K, int Mcols, int bf16_out) {
  __shared__ short As[64 * 40];
  __shared__ short Bs[64 * 40];
  int tid = threadIdx.x;
  int lane = tid & 63, w = tid >> 6;
  int quad = lane >> 4, xn = lane & 15;
  int row0 = blockIdx.y << 6, col0 = blockIdx.x << 6;
  int rw = w & 1, cw = w >> 1;
  int srow = tid >> 2, sk = (tid & 3) << 3;   // staging: row 0..63, k-chunk
  const unsigned short* Ap = A + (size_t)(row0 + srow) * K + sk;
  const unsigned short* Bp = Bw + (size_t)(col0 + srow) * K + sk;
  floatx4 acc[2][2] = {};
  for (int k0 = 0; k0 < K; k0 += 32) {
    uint4 av = *(const uint4*)(Ap + k0);
    uint4 bv = *(const uint4*)(Bp + k0);
    *(uint4*)&As[srow * 40 + sk] = av;
    *(uint4*)&Bs[srow * 40 + sk] = bv;
    __syncthreads();
    bf16x8 af[2], bf[2];
#pragma unroll
    for (int rt = 0; rt < 2; ++rt)
      af[rt] = *(const bf16x8*)&As[(rw * 32 + rt * 16 + xn) * 40 + quad * 8];
#pragma unroll
    for (int ct = 0; ct < 2; ++ct)
      bf[ct] = *(const bf16x8*)&Bs[(cw * 32 + ct * 16 + xn) * 40 + quad * 8];
#pragma unroll
    for (int rt = 0; rt < 2; ++rt)
#pragma unroll
      for (int ct = 0; ct < 2; ++ct)
        acc[rt][ct] = __builtin_amdgcn_mfma_f32_16x16x32_bf16(
            af[rt], bf[ct], acc[rt][ct], 0, 0, 0);
    __syncthreads();
  }
#pragma unroll
  for (int rt = 0; rt < 2; ++rt)
#pragma unroll
    for (int ct = 0; ct < 2; ++ct) {
      int colg = col0 + cw * 32 + ct * 16 + xn;
#pragma unroll
      for (int r = 0; r < 4; ++r) {
        int rowg = row0 + rw * 32 + rt * 16 + quad * 4 + r;
        if (bf16_out)
          ((unsigned short*)Cout)[(size_t)rowg * Mcols + colg] = f2bf(acc[rt][ct][r]);
        else
          ((float*)Cout)[(size_t)rowg * Mcols + colg] = acc[rt][ct][r];
      }
    }
}

// ---------------------------------------------------------------------------
// Scores (MFMA): M[b,h,s,t] = sum_d Q[b,s,h,d]*K[b,t,h,d], Q/K bf16 [B,S,H*DK].
// Output bf16 planar [B,H,S,S]. Tile 128 (s) x 64 (t), K=64 single stage.
// grid (S/64, S/128, B*H), 256 thr = 4 waves, wave = 32 s-rows x 64 t-cols.
// ---------------------------------------------------------------------------
__global__ __launch_bounds__(256) void scores_mfma_kernel(
    const unsigned short* __restrict__ Q, const unsigned short* __restrict__ Km,
    unsigned short* __restrict__ Mo) {
  __shared__ short Qs[128 * 72];
  __shared__ short Ks[64 * 72];
  int z = blockIdx.z, b = z >> 4, h = z & 15;
  int col0 = blockIdx.x << 6, row0 = blockIdx.y << 7;
  int tid = threadIdx.x;
  int lane = tid & 63, w = tid >> 6;
  int quad = lane >> 4, xn = lane & 15;
  const unsigned short* Qb = Q + (size_t)b * S_ * D_ + h * DK_;
  const unsigned short* Kb = Km + (size_t)b * S_ * D_ + h * DK_;
  // stage Q tile: 128 rows x 64 k = 1024 chunks of 8
  for (int idx = tid; idx < 1024; idx += 256) {
    int r = idx >> 3, k8 = (idx & 7) << 3;
    uint4 v = *(const uint4*)&Qb[(size_t)(row0 + r) * D_ + k8];
    *(uint4*)&Qs[r * 72 + k8] = v;
  }
  // stage K tile: 64 rows x 64 k = 512 chunks
  for (int idx = tid; idx < 512; idx += 256) {
    int r = idx >> 3, k8 = (idx & 7) << 3;
    uint4 v = *(const uint4*)&Kb[(size_t)(col0 + r) * D_ + k8];
    *(uint4*)&Ks[r * 72 + k8] = v;
  }
  __syncthreads();
  floatx4 acc[2][4] = {};
#pragma unroll
  for (int ks = 0; ks < 2; ++ks) {
    bf16x8 af[2], bf[4];
#pragma unroll
    for (int rt = 0; rt < 2; ++rt)
      af[rt] = *(const bf16x8*)&Qs[(w * 32 + rt * 16 + xn) * 72 + ks * 32 + quad * 8];
#pragma unroll
    for (int ct = 0; ct < 4; ++ct)
      bf[ct] = *(const bf16x8*)&Ks[(ct * 16 + xn) * 72 + ks * 32 + quad * 8];
#pragma unroll
    for (int rt = 0; rt < 2; ++rt)
#pragma unroll
      for (int ct = 0; ct < 4; ++ct)
        acc[rt][ct] = __builtin_amdgcn_mfma_f32_16x16x32_bf16(
            af[rt], bf[ct], acc[rt][ct], 0, 0, 0);
  }
  unsigned short* Mb = Mo + (size_t)z * S_ * S_;
#pragma unroll
  for (int rt = 0; rt < 2; ++rt)
#pragma unroll
    for (int ct = 0; ct < 4; ++ct) {
      int t = col0 + ct * 16 + xn;
#pragma unroll
      for (int r = 0; r < 4; ++r) {
        int s = row0 + w * 32 + rt * 16 + quad * 4 + r;
        Mb[(size_t)s * S_ + t] = f2bf(acc[rt][ct][r]);
      }
    }
}

// ---------------------------------------------------------------------------
// repack16b: bf16 planar [b][16][Y][X] -> bf16 channel-fastest [b][y][x][16]
// ---------------------------------------------------------------------------
__global__ __launch_bounds__(256) void repack16b_kernel(
    const unsigned short* __restrict__ src, unsigned short* __restrict__ dst) {
  int x = (blockIdx.x << 8) + threadIdx.x;
  int y = blockIdx.y, b = blockIdx.z;
  const unsigned short* sp = src + ((size_t)b * 16 * S_ + y) * S_ + x;
  unsigned short out[16];
#pragma unroll
  for (int c = 0; c < 16; ++c) out[c] = sp[(size_t)c << 20];
  unsigned short* dp = dst + (((size_t)b * S_ + y) * S_ + x) * 16;
  unsigned wds[8];
#pragma unroll
  for (int i = 0; i < 8; ++i)
    wds[i] = (unsigned)out[2 * i] | ((unsigned)out[2 * i + 1] << 16);
  uint4 v0 = {wds[0], wds[1], wds[2], wds[3]};
  uint4 v1 = {wds[4], wds[5], wds[6], wds[7]};
  *(uint4*)dp = v0;
  *((uint4*)dp + 1) = v1;
}

// ---------------------------------------------------------------------------
// repack16: fp32 planar [b][16][Y][X] -> bf16 channel-fastest [b][y][x][16]
// ---------------------------------------------------------------------------
__global__ __launch_bounds__(256) void repack16_kernel(
    const float* __restrict__ src, unsigned short* __restrict__ dst) {
  int x = (blockIdx.x << 8) + threadIdx.x;
  int y = blockIdx.y, b = blockIdx.z;
  const float* sp = src + ((size_t)b * 16 * S_ + y) * S_ + x;
  unsigned short out[16];
#pragma unroll
  for (int c = 0; c < 16; ++c) out[c] = f2bf(sp[(size_t)c << 20]);
  unsigned short* dp = dst + (((size_t)b * S_ + y) * S_ + x) * 16;
  unsigned wds[8];
#pragma unroll
  for (int i = 0; i < 8; ++i)
    wds[i] = (unsigned)out[2 * i] | ((unsigned)out[2 * i + 1] << 16);
  uint4 v0 = {wds[0], wds[1], wds[2], wds[3]};
  uint4 v1 = {wds[4], wds[5], wds[6], wds[7]};
  *(uint4*)dp = v0;
  *((uint4*)dp + 1) = v1;
}

// ---------------------------------------------------------------------------
// conv_t (MFMA): 16ch -> 16ch 3x3 on prevT bf16 ch-fastest. Tile 64x8.
// grid (16, 128, 2). Wave handles 2 rows x 4 segs; K=32 tap-paired MFMAs.
// ---------------------------------------------------------------------------
__global__ __launch_bounds__(256) void conv_t_mfma_kernel(
    const unsigned short* __restrict__ prevT, const float* __restrict__ Wt,
    const float* __restrict__ bt, unsigned short* __restrict__ Mtbf) {
  __shared__ short Xs[10 * 66 * 24];
  int b = blockIdx.z;
  int x0 = blockIdx.x << 6, y0 = blockIdx.y << 3;
  int tid = threadIdx.x;
  int lane = tid & 63, w = tid >> 6;
  int quad = lane >> 4, xn = lane & 15;

  for (int idx = tid; idx < 1320; idx += 256) {
    int y = idx / 132;
    int r = idx - y * 132;
    int px = r >> 1, half = r & 1;
    int gy = y0 + y - 1, gx = x0 + px - 1;
    uint4 val = {0u, 0u, 0u, 0u};
    if ((unsigned)gy < (unsigned)S_ && (unsigned)gx < (unsigned)S_) {
      const unsigned short* sp =
          prevT + (((size_t)b * S_ + gy) * S_ + gx) * 16 + half * 8;
      val = *(const uint4*)sp;
    }
    *(uint4*)&Xs[(y * 66 + px) * 24 + half * 8] = val;
  }

  int m = xn;
  bf16x8 afr[5];
#pragma unroll
  for (int p = 0; p < 5; ++p) {
#pragma unroll
    for (int j = 0; j < 8; ++j) {
      int k = quad * 8 + j;
      int t = 2 * p + (k >> 4);
      float wv = 0.f;
      if (t < 9) wv = Wt[(m * 16 + (k & 15)) * 9 + t];
      afr[p][j] = (short)f2bf(wv);
    }
  }
  int tdy[5], tdx[5];
#pragma unroll
  for (int p = 0; p < 5; ++p) {
    int t = 2 * p + (quad >> 1);
    if (t > 8) t = 8;
    tdy[p] = t / 3;
    tdx[p] = t - tdy[p] * 3;
  }
  float btl[4];
#pragma unroll
  for (int r = 0; r < 4; ++r) btl[r] = bt[quad * 4 + r];

  __syncthreads();

#pragma unroll
  for (int ry = 0; ry < 2; ++ry) {
    int yl = w * 2 + ry;
    int y = y0 + yl;
#pragma unroll
    for (int seg = 0; seg < 4; ++seg) {
      floatx4 acc = {0.f, 0.f, 0.f, 0.f};
#pragma unroll
      for (int p = 0; p < 5; ++p) {
        const short* bp =
            &Xs[((yl + tdy[p]) * 66 + seg * 16 + xn + tdx[p]) * 24 + (quad & 1) * 8];
        bf16x8 bfr = *(const bf16x8*)bp;
        acc = __builtin_amdgcn_mfma_f32_16x16x32_bf16(afr[p], bfr, acc, 0, 0, 0);
      }
      ushort4 pk;
      pk.x = f2bf(acc[0] + btl[0]);
      pk.y = f2bf(acc[1] + btl[1]);
      pk.z = f2bf(acc[2] + btl[2]);
      pk.w = f2bf(acc[3] + btl[3]);
      int gx = x0 + seg * 16 + xn;
      *(ushort4*)&Mtbf[(((size_t)b * S_ + y) * S_ + gx) * 16 + quad * 4] = pk;
    }
  }
}

// ---------------------------------------------------------------------------
// conv_a (MFMA): 32ch -> 16ch 3x3; {Mbf, Mtbf} bf16 ch-fastest. Tile 64x8.
// grid (16, 128, 2). Output planar fp32 into Aout.
// ---------------------------------------------------------------------------
__global__ __launch_bounds__(256) void conv_a_mfma_kernel(
    const unsigned short* __restrict__ Mbf, const unsigned short* __restrict__ Mtbf,
    const float* __restrict__ Wa, const float* __restrict__ ba,
    float* __restrict__ Y) {
  __shared__ short Xs[10 * 66 * 40];
  int b = blockIdx.z;
  int x0 = blockIdx.x << 6, y0 = blockIdx.y << 3;
  int tid = threadIdx.x;
  int lane = tid & 63, w = tid >> 6;
  int quad = lane >> 4, xn = lane & 15;

  for (int idx = tid; idx < 2640; idx += 256) {
    int y = idx / 264;
    int r = idx - y * 264;
    int px = r >> 2, part = r & 3;
    int gy = y0 + y - 1, gx = x0 + px - 1;
    uint4 val = {0u, 0u, 0u, 0u};
    if ((unsigned)gy < (unsigned)S_ && (unsigned)gx < (unsigned)S_) {
      const unsigned short* base = (part < 2) ? Mbf : Mtbf;
      const unsigned short* sp =
          base + (((size_t)b * S_ + gy) * S_ + gx) * 16 + (part & 1) * 8;
      val = *(const uint4*)sp;
    }
    *(uint4*)&Xs[(y * 66 + px) * 40 + part * 8] = val;
  }

  int m = xn;
  bf16x8 afr[9];
#pragma unroll
  for (int t = 0; t < 9; ++t) {
#pragma unroll
    for (int j = 0; j < 8; ++j) {
      int k = quad * 8 + j;
      afr[t][j] = (short)f2bf(Wa[(m * 32 + k) * 9 + t]);
    }
  }
  float bal[4];
#pragma unroll
  for (int r = 0; r < 4; ++r) bal[r] = ba[quad * 4 + r];

  __syncthreads();

#pragma unroll
  for (int ry = 0; ry < 2; ++ry) {
    int yl = w * 2 + ry;
    int y = y0 + yl;
#pragma unroll
    for (int seg = 0; seg < 4; ++seg) {
      floatx4 acc = {0.f, 0.f, 0.f, 0.f};
#pragma unroll
      for (int t = 0; t < 9; ++t) {
        const int dy = t / 3, dx = t - (t / 3) * 3;
        const short* bp =
            &Xs[((yl + dy) * 66 + seg * 16 + xn + dx) * 40 + quad * 8];
        bf16x8 bfr = *(const bf16x8*)bp;
        acc = __builtin_amdgcn_mfma_f32_16x16x32_bf16(afr[t], bfr, acc, 0, 0, 0);
      }
      int gx = x0 + seg * 16 + xn;
#pragma unroll
      for (int r = 0; r < 4; ++r) {
        int mo = quad * 4 + r;
        Y[(((size_t)b * 16 + mo) * S_ + y) * S_ + gx] = acc[r] + bal[r];
      }
    }
  }
}

// ---------------------------------------------------------------------------
// Softmax over last axis of Ma/32 (in place), then POST-softmax masking.
// ---------------------------------------------------------------------------
__global__ __launch_bounds__(256) void softmax_mask_kernel(
    float* __restrict__ A, const int* __restrict__ mask) {
  __shared__ float redm[4], reds[4];
  int row = blockIdx.x;
  int b = row >> 14;
  float* rp = A + (size_t)row * S_;
  int tid = threadIdx.x;
  int t = tid << 2;
  float4 x = *(const float4*)&rp[t];
  const float sc = 1.0f / 32.0f;
  x.x *= sc; x.y *= sc; x.z *= sc; x.w *= sc;
  float m = fmaxf(fmaxf(x.x, x.y), fmaxf(x.z, x.w));
#pragma unroll
  for (int off = 32; off; off >>= 1) m = fmaxf(m, __shfl_down(m, off));
  int lane = tid & 63, w = tid >> 6;
  if (lane == 0) redm[w] = m;
  __syncthreads();
  m = fmaxf(fmaxf(redm[0], redm[1]), fmaxf(redm[2], redm[3]));
  float e0 = __expf(x.x - m), e1 = __expf(x.y - m);
  float e2 = __expf(x.z - m), e3 = __expf(x.w - m);
  float s = e0 + e1 + e2 + e3;
#pragma unroll
  for (int off = 32; off; off >>= 1) s += __shfl_down(s, off);
  if (lane == 0) reds[w] = s;
  __syncthreads();
  s = reds[0] + reds[1] + reds[2] + reds[3];
  float inv = 1.0f / s;
  const int* mb = mask + b * S_;
  float4 o;
  o.x = (mb[t + 0] == 0) ? -1e9f : e0 * inv;
  o.y = (mb[t + 1] == 0) ? -1e9f : e1 * inv;
  o.z = (mb[t + 2] == 0) ? -1e9f : e2 * inv;
  o.w = (mb[t + 3] == 0) ? -1e9f : e3 * inv;
  *(float4*)&rp[t] = o;
}

// ---------------------------------------------------------------------------
// ctx: ctx2[b,s,h*64+d] = sum_t A[b,h,s,t] * V[b,t,h,d]   (fp32)
// ---------------------------------------------------------------------------
__global__ __launch_bounds__(256) void ctx_kernel(
    const float* __restrict__ A, const float* __restrict__ V,
    float* __restrict__ Ctx) {
  __shared__ float As[16][68];
  __shared__ float Vs[16][68];
  int z = blockIdx.y, b = z >> 4, h = z & 15;
  const float* Ab = A + (size_t)z * S_ * S_;
  const float* Vb = V + (size_t)b * S_ * D_ + h * DK_;
  float* Cb = Ctx + (size_t)b * S_ * D_ + h * DK_;
  int tid = threadIdx.x;
  int tx = tid & 15, ty = tid >> 4;
  int row0 = blockIdx.x << 6;
  int lrow = tid >> 2, lk = (tid & 3) << 2;
  int vt = tid >> 4, vd = (tid & 15) << 2;
  float acc[4][4] = {};
  for (int t0 = 0; t0 < S_; t0 += 16) {
    float4 a4 = *(const float4*)&Ab[(size_t)(row0 + lrow) * S_ + t0 + lk];
    As[lk + 0][lrow] = a4.x; As[lk + 1][lrow] = a4.y;
    As[lk + 2][lrow] = a4.z; As[lk + 3][lrow] = a4.w;
    float4 v4 = *(const float4*)&Vb[(size_t)(t0 + vt) * D_ + vd];
    *(float4*)&Vs[vt][vd] = v4;
    __syncthreads();
#pragma unroll
    for (int kk = 0; kk < 16; ++kk) {
      float4 av = *(const float4*)&As[kk][ty << 2];
      float4 bv = *(const float4*)&Vs[kk][tx << 2];
      float a_[4] = {av.x, av.y, av.z, av.w};
      float b_[4] = {bv.x, bv.y, bv.z, bv.w};
#pragma unroll
      for (int i = 0; i < 4; ++i)
#pragma unroll
        for (int j = 0; j < 4; ++j)
          acc[i][j] = fmaf(a_[i], b_[j], acc[i][j]);
    }
    __syncthreads();
  }
#pragma unroll
  for (int i = 0; i < 4; ++i) {
    float4 st = make_float4(acc[i][0], acc[i][1], acc[i][2], acc[i][3]);
    *(float4*)&Cb[(size_t)(row0 + (ty << 2) + i) * D_ + (tx << 2)] = st;
  }
}

// ---------------------------------------------------------------------------
// fp32 NT GEMM (for Wo; ctx2 magnitudes ~1e10 need fp32)
// ---------------------------------------------------------------------------
__global__ __launch_bounds__(256) void gemm_nt_kernel(
    const float* __restrict__ A, const float* __restrict__ Bm,
    float* __restrict__ C, int K, int ldc) {
  __shared__ float As[16][68];
  __shared__ float Bs[16][68];
  int tid = threadIdx.x;
  int tx = tid & 15, ty = tid >> 4;
  int row0 = blockIdx.y << 6, col0 = blockIdx.x << 6;
  int lrow = tid >> 2;
  int lk = (tid & 3) << 2;
  const float* Ap = A + (size_t)(row0 + lrow) * K + lk;
  const float* Bp = Bm + (size_t)(col0 + lrow) * K + lk;
  float acc[4][4] = {};
  for (int k0 = 0; k0 < K; k0 += 16) {
    float4 a4 = *(const float4*)(Ap + k0);
    float4 b4 = *(const float4*)(Bp + k0);
    As[lk + 0][lrow] = a4.x; As[lk + 1][lrow] = a4.y;
    As[lk + 2][lrow] = a4.z; As[lk + 3][lrow] = a4.w;
    Bs[lk + 0][lrow] = b4.x; Bs[lk + 1][lrow] = b4.y;
    Bs[lk + 2][lrow] = b4.z; Bs[lk + 3][lrow] = b4.w;
    __syncthreads();
#pragma unroll
    for (int kk = 0; kk < 16; ++kk) {
      float4 av = *(const float4*)&As[kk][ty << 2];
      float4 bv = *(const float4*)&Bs[kk][tx << 2];
      float a_[4] = {av.x, av.y, av.z, av.w};
      float b_[4] = {bv.x, bv.y, bv.z, bv.w};
#pragma unroll
      for (int i = 0; i < 4; ++i)
#pragma unroll
        for (int j = 0; j < 4; ++j)
          acc[i][j] = fmaf(a_[i], b_[j], acc[i][j]);
    }
    __syncthreads();
  }
#pragma unroll
  for (int i = 0; i < 4; ++i) {
    float4 st = make_float4(acc[i][0], acc[i][1], acc[i][2], acc[i][3]);
    *(float4*)&C[(size_t)(row0 + (ty << 2) + i) * ldc + col0 + (tx << 2)] = st;
  }
}

// ---------------------------------------------------------------------------
extern "C" void kernel_launch(void* const* d_in, const int* in_sizes, int n_in,
                              void* d_out, int out_size, void* d_ws, size_t ws_size,
                              hipStream_t stream) {
  const float* q    = (const float*)d_in[0];
  const float* k    = (const float*)d_in[1];
  const float* v    = (const float*)d_in[2];
  const int*   mask = (const int*)d_in[3];
  const float* prev = (const float*)d_in[4];
  const float* Wq   = (const float*)d_in[5];
  const float* Wk   = (const float*)d_in[6];
  const float* Wv   = (const float*)d_in[7];
  const float* Wo   = (const float*)d_in[8];
  const float* Wt   = (const float*)d_in[9];
  const float* bt   = (const float*)d_in[10];
  const float* Wa   = (const float*)d_in[11];
  const float* ba   = (const float*)d_in[12];

  float* out0 = (float*)d_out;          // [B,S,D]
  float* Aout = out0 + BSD;             // [B,H,S,S]

  // workspace carve (231 MB total; prevT aliases Mp after repack16b)
  char* wsp = (char*)d_ws;
  unsigned short* X1  = (unsigned short*)wsp; wsp += BSD * 2;            // 4 MB
  unsigned short* W1  = (unsigned short*)wsp; wsp += (size_t)D_ * D_ * 2;// 2 MB
  unsigned short* Qb  = (unsigned short*)wsp; wsp += BSD * 2;            // 4 MB
  unsigned short* Kb  = (unsigned short*)wsp; wsp += BSD * 2;            // 4 MB
  float* Vb           = (float*)wsp;          wsp += BSD * 4;            // 8 MB
  float* ctx2         = (float*)wsp;          wsp += BSD * 4;            // 8 MB
  unsigned short* Mp  = (unsigned short*)wsp; wsp += BHSS * 2;           // 67 MB
  unsigned short* Mbf = (unsigned short*)wsp; wsp += BHSS * 2;           // 67 MB
  unsigned short* Mtbf= (unsigned short*)wsp; wsp += BHSS * 2;           // 67 MB
  unsigned short* prevT = Mp;  // alias: prevT written after Mp consumed

  dim3 blk(256);
  int n4x = (int)(BSD / 4);        // q/k/v float4 count
  int n4w = (D_ * D_) / 4;         // weight float4 count
  dim3 gX((n4x + 255) / 256), gW((n4w + 255) / 256);
  dim3 gProjB(D_ / 64, (B_ * S_) / 64);   // bf16 gemm grid (16, 32)

  // Q projection: cvt Wq,q then MFMA gemm -> Qb (bf16)
  hipLaunchKernelGGL(cvt_bf16_kernel, gW, blk, 0, stream, Wq, W1, n4w);
  hipLaunchKernelGGL(cvt_bf16_kernel, gX, blk, 0, stream, q, X1, n4x);
  hipLaunchKernelGGL(gemm_bf16_nt_kernel, gProjB, blk, 0, stream, X1, W1,
                     (void*)Qb, D_, D_, 1);
  // K projection -> Kb (bf16)
  hipLaunchKernelGGL(cvt_bf16_kernel, gW, blk, 0, stream, Wk, W1, n4w);
  hipLaunchKernelGGL(cvt_bf16_kernel, gX, blk, 0, stream, k, X1, n4x);
  hipLaunchKernelGGL(gemm_bf16_nt_kernel, gProjB, blk, 0, stream, X1, W1,
                     (void*)Kb, D_, D_, 1);
  // V projection -> Vb (fp32, feeds fp32 ctx)
  hipLaunchKernelGGL(cvt_bf16_kernel, gW, blk, 0, stream, Wv, W1, n4w);
  hipLaunchKernelGGL(cvt_bf16_kernel, gX, blk, 0, stream, v, X1, n4x);
  hipLaunchKernelGGL(gemm_bf16_nt_kernel, gProjB, blk, 0, stream, X1, W1,
                     (void*)Vb, D_, D_, 0);

  // Scores (MFMA) -> Mp bf16 planar
  dim3 gSc(S_ / 64, S_ / 128, B_ * H_);
  hipLaunchKernelGGL(scores_mfma_kernel, gSc, blk, 0, stream, Qb, Kb, Mp);

  // Repack M -> ch-fastest (must precede prevT write into aliased region)
  dim3 gRep(S_ / 256, S_, B_);
  hipLaunchKernelGGL(repack16b_kernel, gRep, blk, 0, stream, Mp, Mbf);

  // Repack prev -> bf16 ch-fastest (overwrites Mp region)
  hipLaunchKernelGGL(repack16_kernel, gRep, blk, 0, stream, prev, prevT);

  // conv_t (MFMA, 64x8 tile) -> Mtbf
  dim3 gConv(S_ / 64, S_ / 8, B_);
  hipLaunchKernelGGL(conv_t_mfma_kernel, gConv, blk, 0, stream, prevT, Wt, bt, Mtbf);

  // conv_a (MFMA, 64x8 tile) -> Aout planar fp32
  hipLaunchKernelGGL(conv_a_mfma_kernel, gConv, blk, 0, stream, Mbf, Mtbf, Wa, ba, Aout);

  // Softmax(Ma/32) + post-softmax mask, in place
  hipLaunchKernelGGL(softmax_mask_kernel, dim3(B_ * H_ * S_), blk, 0, stream,
                     Aout, mask);

  // ctx = A @ V (fp32: A holds exact -1e9 masked entries)
  dim3 gCtx(S_ / 64, B_ * H_);
  hipLaunchKernelGGL(ctx_kernel, gCtx, blk, 0, stream, Aout, Vb, ctx2);

  // out = ctx2 @ Wo^T (fp32: ctx2 magnitudes ~1e10)
  dim3 gProj(D_ / 64, (B_ * S_) / 64);
  hipLaunchKernelGGL(gemm_nt_kernel, gProj, blk, 0, stream, ctx2, Wo, out0, D_, D_);
}